// Round 13
// baseline (165.101 us; speedup 1.0000x reference)
//
#include <hip/hip_runtime.h>
#include <math.h>

// ---------------------------------------------------------------------------
// HDRL Poincare MLR, c=1.
//   arg = 2*(Bc*xa - Aq*pa) / (Bc*(1-x2)*an),  Aq = 1+x2-2px, Bc = 1-p2
//   out = copysign(asinh(|arg|), arg) * an      (Dd cancels exactly; Dd>0)
// px = <x_b, p_o>, xa = <x_b, a_o> via dual bf16 MFMA GEMM (shared x tiles).
//
// R12 "fat waves": measured port throughput ~50 B/cyc across R5/R7/R8/R11
//   shows the LDS port is the binding resource, so CUT PORT TRAFFIC instead
//   of rescheduling it. 4 waves (1/SIMD), each owning 128 rows x 64 dual
//   cols: A-fragment read redundancy drops 4x -> 2x; per-K-tile port traffic
//   256 KB -> 192 KB (-25%). acc 256 + frags 128 VGPR fits the 512 budget at
//   __launch_bounds__(256,1). Simple R5-style 1-barrier loop (schedule
//   variants were all noise; in-wave ILP + compiler lgkm interleave carries
//   the overlap). Keeps: XCD stripe, XOR swizzle, fast epilogue (verified).
// ---------------------------------------------------------------------------

#define B_DIM 8192
#define O_DIM 4096
#define K_DIM 1024

using f32x4  = __attribute__((ext_vector_type(4))) float;
using bf16x8 = __attribute__((ext_vector_type(8))) short;

__device__ inline unsigned short f2bf(float f) {
  union { float f; unsigned u; } v; v.f = f;
  unsigned u = v.u;
  u += 0x7FFFu + ((u >> 16) & 1u);   // RNE
  return (unsigned short)(u >> 16);
}

__device__ inline void load_lds16(const void* g, void* l) {
  __builtin_amdgcn_global_load_lds(
      (const __attribute__((address_space(1))) void*)g,
      (__attribute__((address_space(3))) void*)l, 16, 0, 0);
}

__device__ inline float frcp(float x)  { float r; asm("v_rcp_f32 %0, %1"  : "=v"(r) : "v"(x)); return r; }
__device__ inline float fsqrt_(float x){ float r; asm("v_sqrt_f32 %0, %1" : "=v"(r) : "v"(x)); return r; }
__device__ inline float flog2(float x) { float r; asm("v_log_f32 %0, %1"  : "=v"(r) : "v"(x)); return r; }

// ---- per-output-row stats + bf16 conversion (weight & projected bias) -----
__global__ __launch_bounds__(256) void prep_rows(
    const float* __restrict__ wgt, const float* __restrict__ bia,
    unsigned short* __restrict__ a_bf, unsigned short* __restrict__ p_bf,
    float* __restrict__ p2v, float* __restrict__ pav, float* __restrict__ anv)
{
  const int o = blockIdx.x, t = threadIdx.x;
  const float4 w = ((const float4*)(wgt + (size_t)o * K_DIM))[t];
  const float4 b = ((const float4*)(bia + (size_t)o * K_DIM))[t];
  float a2 = w.x*w.x + w.y*w.y + w.z*w.z + w.w*w.w;
  float b2 = b.x*b.x + b.y*b.y + b.z*b.z + b.w*b.w;
  float ab = w.x*b.x + w.y*b.y + w.z*b.z + w.w*b.w;
  #pragma unroll
  for (int off = 32; off; off >>= 1) {
    a2 += __shfl_down(a2, off);
    b2 += __shfl_down(b2, off);
    ab += __shfl_down(ab, off);
  }
  __shared__ float sa[4], sb[4], sc_[4];
  const int wv = t >> 6, ln = t & 63;
  if (ln == 0) { sa[wv] = a2; sb[wv] = b2; sc_[wv] = ab; }
  __syncthreads();
  const float A2 = sa[0] + sa[1] + sa[2] + sa[3];
  const float B2 = sb[0] + sb[1] + sb[2] + sb[3];
  const float AB = sc_[0] + sc_[1] + sc_[2] + sc_[3];
  const float norm = sqrtf(B2);
  const float maxn = 1.0f - 1e-5f;            // (1-PROJ_EPS)/sqrt(c), c=1
  const float s = (norm > maxn) ? (maxn / norm) : 1.0f;
  if (t == 0) { p2v[o] = B2 * s * s; pav[o] = AB * s; anv[o] = sqrtf(A2); }
  unsigned short* ao = a_bf + (size_t)o * K_DIM + t * 4;
  unsigned short* po = p_bf + (size_t)o * K_DIM + t * 4;
  ao[0] = f2bf(w.x); ao[1] = f2bf(w.y); ao[2] = f2bf(w.z); ao[3] = f2bf(w.w);
  po[0] = f2bf(b.x * s); po[1] = f2bf(b.y * s); po[2] = f2bf(b.z * s); po[3] = f2bf(b.w * s);
}

// ---- per-batch-row stats + bf16 conversion of x ---------------------------
__global__ __launch_bounds__(256) void prep_x(
    const float* __restrict__ x, unsigned short* __restrict__ x_bf,
    float* __restrict__ x2v)
{
  const int bi = blockIdx.x, t = threadIdx.x;
  const float4 v = ((const float4*)(x + (size_t)bi * K_DIM))[t];
  float s2 = v.x*v.x + v.y*v.y + v.z*v.z + v.w*v.w;
  #pragma unroll
  for (int off = 32; off; off >>= 1) s2 += __shfl_down(s2, off);
  __shared__ float sl[4];
  const int wv = t >> 6, ln = t & 63;
  if (ln == 0) sl[wv] = s2;
  __syncthreads();
  if (t == 0) x2v[bi] = sl[0] + sl[1] + sl[2] + sl[3];
  unsigned short* xo = x_bf + (size_t)bi * K_DIM + t * 4;
  xo[0] = f2bf(v.x); xo[1] = f2bf(v.y); xo[2] = f2bf(v.z); xo[3] = f2bf(v.w);
}

// ---- main dual-GEMM + fused epilogue ---------------------------------------
// 4 waves (2M x 2N), 1 wave/SIMD. BM=256, BN=128 (dual P/W), BK=64, 16 tiles.
// Wave = 128 rows x 64 cols of BOTH P and W: acc = accp[8][4]+acca[8][4]
// f32x4 = 256 VGPR; frags af[8][2]+bp[4][2]+bw[4][2] = 128 VGPR. 512 budget.
// LDS per buffer (bf16 elems): A[256*64] @0, P[128*64] @16384, W @24576;
// 2 buffers = 128 KB. Per-tile port traffic: 128 KB reads + 64 KB writes
// (was 192+64 with 8 waves). One __syncthreads per K-tile (dbuf).
__global__ __launch_bounds__(256, 1) void hdrl_main(
    const unsigned short* __restrict__ Xb,
    const unsigned short* __restrict__ Pb,
    const unsigned short* __restrict__ Ab,
    const float* __restrict__ x2v, const float* __restrict__ p2v,
    const float* __restrict__ pav, const float* __restrict__ anv,
    float* __restrict__ out)
{
  extern __shared__ unsigned short lds[];

  const int bid   = blockIdx.x;
  const int xcd   = bid & 7;
  const int local = bid >> 3;                 // 0..127 per XCD
  const int nt    = xcd * 4 + (local & 3);    // 4 n-columns per XCD
  const int mt    = local >> 2;               // 0..31
  const int row0 = mt * 256, col0 = nt * 128;
  const int t    = threadIdx.x;
  const int wv   = t >> 6, lane = t & 63;
  const int wm   = wv >> 1, wn = wv & 1;      // 2M x 2N waves
  const int lrow = lane & 15, kg = lane >> 4;
  const int sw   = (lrow & 7) << 3;           // read-side XOR key (elems)
  const int kbs0 = (kg * 8) ^ sw;
  const int kbs1 = (32 + kg * 8) ^ sw;

  // staging: thread t covers row sr (of 32 per gload), swizzled 16B chunk
  const int sr   = t >> 3;                    // 0..31
  const int scol = ((t & 7) ^ (sr & 7)) * 8;  // inverse-swizzled source col
  const unsigned short* gA = Xb + (size_t)(row0 + sr) * K_DIM + scol;
  const unsigned short* gP = Pb + (size_t)(col0 + sr) * K_DIM + scol;
  const unsigned short* gW = Ab + (size_t)(col0 + sr) * K_DIM + scol;

  f32x4 accp[8][4], acca[8][4];
  #pragma unroll
  for (int i = 0; i < 8; ++i)
    #pragma unroll
    for (int j = 0; j < 4; ++j) { accp[i][j] = (f32x4)0.0f; acca[i][j] = (f32x4)0.0f; }

  // one gload = 4 waves x 1024 B = 4 KB = 32 rows of 64 bf16
#define STG(dst, src, q, kel) \
  load_lds16((src) + (size_t)(q) * 32 * K_DIM + (kel), \
             (void*)&lds[(dst) + (q) * 2048 + wv * 512])

  // prologue: stage tile 0 into buffer 0
  {
    #pragma unroll
    for (int q = 0; q < 8; ++q) STG(0, gA, q, 0);
    #pragma unroll
    for (int q = 0; q < 4; ++q) { STG(16384, gP, q, 0); STG(24576, gW, q, 0); }
  }
  __syncthreads();

  for (int kt = 0; kt < 16; ++kt) {
    const int cb  = (kt & 1) << 15;            // 0 / 32768
    const int nb  = cb ^ 32768;
    const int k0n = (kt + 1) * 64;

    // stage next tile first: loads get the whole compute phase to land
    if (kt < 15) {
      #pragma unroll
      for (int q = 0; q < 8; ++q) STG(nb, gA, q, k0n);
      #pragma unroll
      for (int q = 0; q < 4; ++q) { STG(nb + 16384, gP, q, k0n);
                                    STG(nb + 24576, gW, q, k0n); }
    }

    // fragments (32 ds_read_b128/wave; conflict-free via XOR swizzle)
    bf16x8 af[8][2], bp[4][2], bw[4][2];
    #pragma unroll
    for (int i = 0; i < 8; ++i) {
      const int rr = cb + (wm * 128 + i * 16 + lrow) * 64;
      af[i][0] = *(const bf16x8*)&lds[rr + kbs0];
      af[i][1] = *(const bf16x8*)&lds[rr + kbs1];
    }
    #pragma unroll
    for (int j = 0; j < 4; ++j) {
      const int rb = (wn * 64 + j * 16 + lrow) * 64;
      bp[j][0] = *(const bf16x8*)&lds[cb + 16384 + rb + kbs0];
      bp[j][1] = *(const bf16x8*)&lds[cb + 16384 + rb + kbs1];
      bw[j][0] = *(const bf16x8*)&lds[cb + 24576 + rb + kbs0];
      bw[j][1] = *(const bf16x8*)&lds[cb + 24576 + rb + kbs1];
    }

    // 128 MFMA/wave; compiler interleaves lgkm waits (m97-verified)
    __builtin_amdgcn_s_setprio(1);
    #pragma unroll
    for (int kk = 0; kk < 2; ++kk)
      #pragma unroll
      for (int i = 0; i < 8; ++i)
        #pragma unroll
        for (int j = 0; j < 4; ++j) {
          accp[i][j] = __builtin_amdgcn_mfma_f32_16x16x32_bf16(af[i][kk], bp[j][kk], accp[i][j], 0, 0, 0);
          acca[i][j] = __builtin_amdgcn_mfma_f32_16x16x32_bf16(af[i][kk], bw[j][kk], acca[i][j], 0, 0, 0);
        }
    __builtin_amdgcn_s_setprio(0);

    __syncthreads();   // drains vmcnt+lgkmcnt: next buffer fully resident
  }

  // fused epilogue: C/D layout col = lane&15, row = (lane>>4)*4 + reg.
  // arg = 2*(Bc*xa - Aq*pa) / (Bc*(1-x2)*an); out = copysign(asinh|arg|,arg)*an
  float Bcj[4], paj[4], dja[4], lcj[4];
  #pragma unroll
  for (int j = 0; j < 4; ++j) {
    const int col = col0 + wn * 64 + j * 16 + lrow;
    const float Bc = 1.0f - p2v[col];
    const float an = anv[col];
    Bcj[j] = Bc; paj[j] = pav[col];
    dja[j] = Bc * an;                 // denom col factor
    lcj[j] = 0.69314718f * an;        // ln2 * a_norm
  }
  #pragma unroll
  for (int i = 0; i < 8; ++i) {
    const int rbase = row0 + wm * 128 + i * 16 + kg * 4;
    #pragma unroll
    for (int r = 0; r < 4; ++r) {
      const int row = rbase + r;
      const float x2 = x2v[row];
      const float Aqh = 1.0f + x2;
      const float omx = 1.0f - x2;
      float* orow = out + (size_t)row * O_DIM + col0 + wn * 64 + lrow;
      #pragma unroll
      for (int j = 0; j < 4; ++j) {
        const float px = accp[i][j][r];
        const float xa = acca[i][j][r];
        const float numer = Bcj[j] * xa - (Aqh - 2.0f * px) * paj[j];
        const float denom = dja[j] * omx + 1e-15f;
        const float arg = 2.0f * numer * frcp(denom);
        const float aa  = fabsf(arg);
        const float u   = aa + fsqrt_(__builtin_fmaf(aa, aa, 1.0f));
        orow[j * 16] = copysignf(flog2(u) * lcj[j], arg);
      }
    }
  }
#undef STG
}

extern "C" void kernel_launch(void* const* d_in, const int* in_sizes, int n_in,
                              void* d_out, int out_size, void* d_ws, size_t ws_size,
                              hipStream_t stream) {
  (void)in_sizes; (void)n_in; (void)out_size; (void)ws_size;
  const float* x = (const float*)d_in[0];
  const float* w = (const float*)d_in[1];
  const float* b = (const float*)d_in[2];
  float* out = (float*)d_out;

  char* ws = (char*)d_ws;
  unsigned short* x_bf = (unsigned short*)ws;                               // 16 MB
  unsigned short* p_bf = (unsigned short*)(ws + (size_t)16 * 1024 * 1024);  //  8 MB
  unsigned short* a_bf = (unsigned short*)(ws + (size_t)24 * 1024 * 1024);  //  8 MB
  float* p2v = (float*)(ws + (size_t)32 * 1024 * 1024);
  float* pav = p2v + O_DIM;
  float* anv = pav + O_DIM;
  float* x2v = anv + O_DIM;

  prep_rows<<<O_DIM, 256, 0, stream>>>(w, b, a_bf, p_bf, p2v, pav, anv);
  prep_x<<<B_DIM, 256, 0, stream>>>(x, x_bf, x2v);

  hipFuncSetAttribute((const void*)hdrl_main,
                      hipFuncAttributeMaxDynamicSharedMemorySize, 131072);
  const int grid = (B_DIM / 256) * (O_DIM / 128);   // 1024
  hdrl_main<<<grid, 256, 131072, stream>>>(x_bf, p_bf, a_bf, x2v, p2v, pav, anv, out);
}

// Round 14
// 148.131 us; speedup vs baseline: 1.1146x; 1.1146x over previous
//
#include <hip/hip_runtime.h>
#include <math.h>

// ---------------------------------------------------------------------------
// HDRL Poincare MLR, c=1.
//   arg = 2*(Bc*xa - Aq*pa) / (Bc*(1-x2)*an),  Aq = 1+x2-2px, Bc = 1-p2
//   out = copysign(asinh(|arg|), arg) * an      (Dd cancels exactly; Dd>0)
// px = <x_b, p_o>, xa = <x_b, a_o> via dual bf16 MFMA GEMM (shared x tiles).
//
// R13 consolidation on R7 (best: 136.3 us main / 148.06 total):
//   * merged prep kernel (one launch instead of two)
//   * SGB counts fixed to the true chunk stream: 4 DS_READ + 32 MFMA
//   * core loop byte-identical to R7 otherwise.
// Ledger note: effective LDS port rate is ~50 B/cyc across ALL >=2-wave/SIMD
// schedules tried (R5/R7/R8/R9/R11); schedule shape is not the lever here.
// ---------------------------------------------------------------------------

#define B_DIM 8192
#define O_DIM 4096
#define K_DIM 1024

using f32x4  = __attribute__((ext_vector_type(4))) float;
using bf16x8 = __attribute__((ext_vector_type(8))) short;

__device__ inline unsigned short f2bf(float f) {
  union { float f; unsigned u; } v; v.f = f;
  unsigned u = v.u;
  u += 0x7FFFu + ((u >> 16) & 1u);   // RNE
  return (unsigned short)(u >> 16);
}

__device__ inline void load_lds16(const void* g, void* l) {
  __builtin_amdgcn_global_load_lds(
      (const __attribute__((address_space(1))) void*)g,
      (__attribute__((address_space(3))) void*)l, 16, 0, 0);
}

__device__ inline float frcp(float x)  { float r; asm("v_rcp_f32 %0, %1"  : "=v"(r) : "v"(x)); return r; }
__device__ inline float fsqrt_(float x){ float r; asm("v_sqrt_f32 %0, %1" : "=v"(r) : "v"(x)); return r; }
__device__ inline float flog2(float x) { float r; asm("v_log_f32 %0, %1"  : "=v"(r) : "v"(x)); return r; }

// ---- merged prep: blocks [0, O_DIM) do weight/bias rows; rest do x rows ----
__global__ __launch_bounds__(256) void prep_all(
    const float* __restrict__ x, const float* __restrict__ wgt,
    const float* __restrict__ bia,
    unsigned short* __restrict__ x_bf, unsigned short* __restrict__ a_bf,
    unsigned short* __restrict__ p_bf,
    float* __restrict__ x2v, float* __restrict__ p2v,
    float* __restrict__ pav, float* __restrict__ anv)
{
  const int t = threadIdx.x;
  const int wv = t >> 6, ln = t & 63;
  __shared__ float sa[4], sb[4], sc_[4];

  if (blockIdx.x < O_DIM) {
    const int o = blockIdx.x;
    const float4 w = ((const float4*)(wgt + (size_t)o * K_DIM))[t];
    const float4 b = ((const float4*)(bia + (size_t)o * K_DIM))[t];
    float a2 = w.x*w.x + w.y*w.y + w.z*w.z + w.w*w.w;
    float b2 = b.x*b.x + b.y*b.y + b.z*b.z + b.w*b.w;
    float ab = w.x*b.x + w.y*b.y + w.z*b.z + w.w*b.w;
    #pragma unroll
    for (int off = 32; off; off >>= 1) {
      a2 += __shfl_down(a2, off);
      b2 += __shfl_down(b2, off);
      ab += __shfl_down(ab, off);
    }
    if (ln == 0) { sa[wv] = a2; sb[wv] = b2; sc_[wv] = ab; }
    __syncthreads();
    const float A2 = sa[0] + sa[1] + sa[2] + sa[3];
    const float B2 = sb[0] + sb[1] + sb[2] + sb[3];
    const float AB = sc_[0] + sc_[1] + sc_[2] + sc_[3];
    const float norm = sqrtf(B2);
    const float maxn = 1.0f - 1e-5f;          // (1-PROJ_EPS)/sqrt(c), c=1
    const float s = (norm > maxn) ? (maxn / norm) : 1.0f;
    if (t == 0) { p2v[o] = B2 * s * s; pav[o] = AB * s; anv[o] = sqrtf(A2); }
    unsigned short* ao = a_bf + (size_t)o * K_DIM + t * 4;
    unsigned short* po = p_bf + (size_t)o * K_DIM + t * 4;
    ao[0] = f2bf(w.x); ao[1] = f2bf(w.y); ao[2] = f2bf(w.z); ao[3] = f2bf(w.w);
    po[0] = f2bf(b.x * s); po[1] = f2bf(b.y * s); po[2] = f2bf(b.z * s); po[3] = f2bf(b.w * s);
  } else {
    const int bi = blockIdx.x - O_DIM;
    const float4 v = ((const float4*)(x + (size_t)bi * K_DIM))[t];
    float s2 = v.x*v.x + v.y*v.y + v.z*v.z + v.w*v.w;
    #pragma unroll
    for (int off = 32; off; off >>= 1) s2 += __shfl_down(s2, off);
    if (ln == 0) sa[wv] = s2;
    __syncthreads();
    if (t == 0) x2v[bi] = sa[0] + sa[1] + sa[2] + sa[3];
    unsigned short* xo = x_bf + (size_t)bi * K_DIM + t * 4;
    xo[0] = f2bf(v.x); xo[1] = f2bf(v.y); xo[2] = f2bf(v.z); xo[3] = f2bf(v.w);
  }
}

// ---- main dual-GEMM + fused epilogue ---------------------------------------
// 8 waves (4M x 2N). BM=256, BN=128 (dual P/W), BK=64. 16 K-tiles.
// LDS per buffer (bf16 elems): A[256*64]=16384 @0, P[128*64]=8192 @16384,
// W[128*64]=8192 @24576; buffer stride 32768 elems; 2 buffers = 128 KB.
// XCD column-stripe: xcd = bid&7 owns nt in [xcd*4, xcd*4+4).
// One __syncthreads per K-tile; SGB pins [DS4 | MFMA32] chunk interleave.
__global__ __launch_bounds__(512, 2) void hdrl_main(
    const unsigned short* __restrict__ Xb,
    const unsigned short* __restrict__ Pb,
    const unsigned short* __restrict__ Ab,
    const float* __restrict__ x2v, const float* __restrict__ p2v,
    const float* __restrict__ pav, const float* __restrict__ anv,
    float* __restrict__ out)
{
  extern __shared__ unsigned short lds[];

  const int bid   = blockIdx.x;
  const int xcd   = bid & 7;
  const int local = bid >> 3;                 // 0..127 per XCD
  const int nt    = xcd * 4 + (local & 3);    // 4 n-columns per XCD
  const int mt    = local >> 2;               // 0..31
  const int row0 = mt * 256, col0 = nt * 128;
  const int t    = threadIdx.x;
  const int wv   = t >> 6, lane = t & 63;
  const int wm   = wv >> 1, wn = wv & 1;      // 4M x 2N waves
  const int lrow = lane & 15, kg = lane >> 4;
  const int sw   = (lrow & 7) << 3;           // read-side XOR key (elems)

  // staging: thread t covers chunk (r = q*64 + (t>>3), c = t&7), 16B chunks
  const int sr   = t >> 3;                    // 0..63
  const int sc   = t & 7;
  const int scol = (sc ^ (sr & 7)) * 8;       // inverse-swizzled source col
  const unsigned short* gA = Xb + (size_t)(row0 + sr) * K_DIM + scol;
  const unsigned short* gP = Pb + (size_t)(col0 + sr) * K_DIM + scol;
  const unsigned short* gW = Ab + (size_t)(col0 + sr) * K_DIM + scol;

  f32x4 accp[4][4], acca[4][4];
  #pragma unroll
  for (int i = 0; i < 4; ++i)
    #pragma unroll
    for (int j = 0; j < 4; ++j) { accp[i][j] = (f32x4)0.0f; acca[i][j] = (f32x4)0.0f; }

#define STAGE_A(q) load_lds16(gA + (size_t)(q)*64*K_DIM + k0n, (void*)&lds[nb + (q)*4096 + wv*512])
#define STAGE_P(q) load_lds16(gP + (size_t)(q)*64*K_DIM + k0n, (void*)&lds[nb + 16384 + (q)*4096 + wv*512])
#define STAGE_W(q) load_lds16(gW + (size_t)(q)*64*K_DIM + k0n, (void*)&lds[nb + 24576 + (q)*4096 + wv*512])

  // prologue: stage tile 0 into buffer 0
  {
    const int nb = 0, k0n = 0;
    STAGE_A(0); STAGE_A(1); STAGE_A(2); STAGE_A(3);
    STAGE_P(0); STAGE_P(1); STAGE_W(0); STAGE_W(1);
  }
  __syncthreads();

  for (int kt = 0; kt < 16; ++kt) {
    const int cur = kt & 1;
    const int nb  = (cur ^ 1) * 32768;
    const int cb  = cur * 32768;
    const int k0n = (kt + 1) * 64;

    // stage next tile first: loads get the whole compute phase to land
    if (kt < 15) {
      STAGE_A(0); STAGE_A(1); STAGE_A(2); STAGE_A(3);
      STAGE_P(0); STAGE_P(1); STAGE_W(0); STAGE_W(1);
    }

    const int kbs0 = (kg * 8) ^ sw;
    const int kbs1 = (32 + kg * 8) ^ sw;
    bf16x8 af[4][2], bp[4][2], bw[4][2];
    #pragma unroll
    for (int i = 0; i < 4; ++i) {
      af[i][0] = *(const bf16x8*)&lds[cb + (wm*64 + i*16 + lrow)*64 + kbs0];
      af[i][1] = *(const bf16x8*)&lds[cb + (wm*64 + i*16 + lrow)*64 + kbs1];
    }
    bp[0][0] = *(const bf16x8*)&lds[cb + 16384 + (wn*64 + 0*16 + lrow)*64 + kbs0];
    bp[0][1] = *(const bf16x8*)&lds[cb + 16384 + (wn*64 + 0*16 + lrow)*64 + kbs1];
    bw[0][0] = *(const bf16x8*)&lds[cb + 24576 + (wn*64 + 0*16 + lrow)*64 + kbs0];
    bw[0][1] = *(const bf16x8*)&lds[cb + 24576 + (wn*64 + 0*16 + lrow)*64 + kbs1];
    // pin: the 12 warm-up DS_READs stay ahead of the MFMA stream
    __builtin_amdgcn_sched_group_barrier(0x100, 12, 0);   // DS_READ x12

    __builtin_amdgcn_s_setprio(1);
    #pragma unroll
    for (int j = 0; j < 4; ++j) {
      if (j < 3) {   // prefetch next j's B frags (4 DS_READ)
        bp[j+1][0] = *(const bf16x8*)&lds[cb + 16384 + (wn*64 + (j+1)*16 + lrow)*64 + kbs0];
        bp[j+1][1] = *(const bf16x8*)&lds[cb + 16384 + (wn*64 + (j+1)*16 + lrow)*64 + kbs1];
        bw[j+1][0] = *(const bf16x8*)&lds[cb + 24576 + (wn*64 + (j+1)*16 + lrow)*64 + kbs0];
        bw[j+1][1] = *(const bf16x8*)&lds[cb + 24576 + (wn*64 + (j+1)*16 + lrow)*64 + kbs1];
      }
      #pragma unroll
      for (int i = 0; i < 4; ++i)
        #pragma unroll
        for (int kk = 0; kk < 2; ++kk)
          accp[i][j] = __builtin_amdgcn_mfma_f32_16x16x32_bf16(af[i][kk], bp[j][kk], accp[i][j], 0, 0, 0);
      #pragma unroll
      for (int i = 0; i < 4; ++i)
        #pragma unroll
        for (int kk = 0; kk < 2; ++kk)
          acca[i][j] = __builtin_amdgcn_mfma_f32_16x16x32_bf16(af[i][kk], bw[j][kk], acca[i][j], 0, 0, 0);
      // chunk stream: 4 DS_READ (next j) then ALL 32 MFMA of this j
      if (j < 3) __builtin_amdgcn_sched_group_barrier(0x100, 4, 0);  // DS_READ x4
      __builtin_amdgcn_sched_group_barrier(0x8, 32, 0);              // MFMA x32
    }
    __builtin_amdgcn_s_setprio(0);

    __syncthreads();   // drains vmcnt+lgkmcnt: next buffer fully resident
  }

  // fused epilogue: C/D layout col = lane&15, row = (lane>>4)*4 + reg.
  // arg = 2*(Bc*xa - Aq*pa) / (Bc*(1-x2)*an); out = copysign(asinh|arg|,arg)*an
  float Bcj[4], paj[4], dja[4], lcj[4];
  #pragma unroll
  for (int j = 0; j < 4; ++j) {
    const int col = col0 + wn * 64 + j * 16 + lrow;
    const float Bc = 1.0f - p2v[col];
    const float an = anv[col];
    Bcj[j] = Bc; paj[j] = pav[col];
    dja[j] = Bc * an;                 // denom col factor
    lcj[j] = 0.69314718f * an;        // ln2 * a_norm
  }
  #pragma unroll
  for (int i = 0; i < 4; ++i) {
    const int rbase = row0 + wm * 64 + i * 16 + kg * 4;
    #pragma unroll
    for (int r = 0; r < 4; ++r) {
      const int row = rbase + r;
      const float x2 = x2v[row];
      const float Aqh = 1.0f + x2;
      const float omx = 1.0f - x2;
      float* orow = out + (size_t)row * O_DIM + col0 + wn * 64 + lrow;
      #pragma unroll
      for (int j = 0; j < 4; ++j) {
        const float px = accp[i][j][r];
        const float xa = acca[i][j][r];
        const float numer = Bcj[j] * xa - (Aqh - 2.0f * px) * paj[j];
        const float denom = dja[j] * omx + 1e-15f;
        const float arg = 2.0f * numer * frcp(denom);
        const float aa  = fabsf(arg);
        const float u   = aa + fsqrt_(__builtin_fmaf(aa, aa, 1.0f));
        orow[j * 16] = copysignf(flog2(u) * lcj[j], arg);
      }
    }
  }
#undef STAGE_A
#undef STAGE_P
#undef STAGE_W
}

extern "C" void kernel_launch(void* const* d_in, const int* in_sizes, int n_in,
                              void* d_out, int out_size, void* d_ws, size_t ws_size,
                              hipStream_t stream) {
  (void)in_sizes; (void)n_in; (void)out_size; (void)ws_size;
  const float* x = (const float*)d_in[0];
  const float* w = (const float*)d_in[1];
  const float* b = (const float*)d_in[2];
  float* out = (float*)d_out;

  char* ws = (char*)d_ws;
  unsigned short* x_bf = (unsigned short*)ws;                               // 16 MB
  unsigned short* p_bf = (unsigned short*)(ws + (size_t)16 * 1024 * 1024);  //  8 MB
  unsigned short* a_bf = (unsigned short*)(ws + (size_t)24 * 1024 * 1024);  //  8 MB
  float* p2v = (float*)(ws + (size_t)32 * 1024 * 1024);
  float* pav = p2v + O_DIM;
  float* anv = pav + O_DIM;
  float* x2v = anv + O_DIM;

  prep_all<<<O_DIM + B_DIM, 256, 0, stream>>>(x, w, b, x_bf, a_bf, p_bf,
                                              x2v, p2v, pav, anv);

  hipFuncSetAttribute((const void*)hdrl_main,
                      hipFuncAttributeMaxDynamicSharedMemorySize, 131072);
  const int grid = (B_DIM / 256) * (O_DIM / 128);   // 1024
  hdrl_main<<<grid, 512, 131072, stream>>>(x_bf, p_bf, a_bf, x2v, p2v, pav, anv, out);
}

// Round 15
// 101.309 us; speedup vs baseline: 1.6297x; 1.4622x over previous
//
#include <hip/hip_runtime.h>
#include <math.h>

// ---------------------------------------------------------------------------
// HDRL Poincare MLR, c=1.
//   arg = 2*(Bc*xa - Aq*pa) / (Bc*(1-x2)*an),  Aq = 1+x2-2px, Bc = 1-p2
//   out = copysign(asinh(|arg|), arg) * an      (Dd cancels exactly; Dd>0)
// px = <x_b, p_o>, xa = <x_b, a_o> via dual INT8 MFMA GEMM (shared x tiles).
//
// R14: int8 GEMM. Per-row symmetric quantization (q = round(v*127/rowmax),
//   fp32 scales; int32 accumulate is exact; epilogue applies sx*sp / sx*sa).
//   mfma_i32_16x16x64_i8 = 2x K per instr AND rows 2KB->1KB, so LDS port
//   bytes (the measured ~50 B/cyc binding resource, R5-R13) HALVE.
//   Byte-level layout identical to R7/R13: 16B lane k-slices, 128B rows per
//   K-tile, same staging/swizzle/fragment/epilogue addressing; 8 K-tiles.
//   Precision: predicted absmax 0.16-0.25 vs threshold 0.3475 (see ledger).
// ---------------------------------------------------------------------------

#define B_DIM 8192
#define O_DIM 4096
#define K_DIM 1024
#define KB    1024   // bytes per row in i8

using i32x4 = __attribute__((ext_vector_type(4))) int;

__device__ inline unsigned short f2bf(float f) {
  union { float f; unsigned u; } v; v.f = f;
  unsigned u = v.u;
  u += 0x7FFFu + ((u >> 16) & 1u);
  return (unsigned short)(u >> 16);
}

__device__ inline void load_lds16(const void* g, void* l) {
  __builtin_amdgcn_global_load_lds(
      (const __attribute__((address_space(1))) void*)g,
      (__attribute__((address_space(3))) void*)l, 16, 0, 0);
}

__device__ inline float frcp(float x)  { float r; asm("v_rcp_f32 %0, %1"  : "=v"(r) : "v"(x)); return r; }
__device__ inline float fsqrt_(float x){ float r; asm("v_sqrt_f32 %0, %1" : "=v"(r) : "v"(x)); return r; }
__device__ inline float flog2(float x) { float r; asm("v_log_f32 %0, %1"  : "=v"(r) : "v"(x)); return r; }

__device__ inline int pack4(int a, int b, int c, int d) {
  return (a & 0xFF) | ((b & 0xFF) << 8) | ((c & 0xFF) << 16) | (d << 24);
}

// ---- merged prep: blocks [0, O_DIM) do weight/bias rows; rest do x rows ----
// Quantize per-row: scale = rowmax/127 (fp32), q = round(v*127/rowmax).
__global__ __launch_bounds__(256) void prep_all(
    const float* __restrict__ x, const float* __restrict__ wgt,
    const float* __restrict__ bia,
    int* __restrict__ x_q, int* __restrict__ a_q, int* __restrict__ p_q,
    float* __restrict__ x2v, float* __restrict__ p2v,
    float* __restrict__ pav, float* __restrict__ anv,
    float* __restrict__ sxv, float* __restrict__ sav, float* __restrict__ spv)
{
  const int t = threadIdx.x;
  const int wv = t >> 6, ln = t & 63;
  __shared__ float s0[4], s1[4], s2_[4], s3[4], s4[4];

  if (blockIdx.x < O_DIM) {
    const int o = blockIdx.x;
    const float4 w = ((const float4*)(wgt + (size_t)o * K_DIM))[t];
    const float4 b = ((const float4*)(bia + (size_t)o * K_DIM))[t];
    float a2 = w.x*w.x + w.y*w.y + w.z*w.z + w.w*w.w;
    float b2 = b.x*b.x + b.y*b.y + b.z*b.z + b.w*b.w;
    float ab = w.x*b.x + w.y*b.y + w.z*b.z + w.w*b.w;
    float mw = fmaxf(fmaxf(fabsf(w.x), fabsf(w.y)), fmaxf(fabsf(w.z), fabsf(w.w)));
    float mb = fmaxf(fmaxf(fabsf(b.x), fabsf(b.y)), fmaxf(fabsf(b.z), fabsf(b.w)));
    #pragma unroll
    for (int off = 32; off; off >>= 1) {
      a2 += __shfl_down(a2, off);
      b2 += __shfl_down(b2, off);
      ab += __shfl_down(ab, off);
      mw = fmaxf(mw, __shfl_down(mw, off));
      mb = fmaxf(mb, __shfl_down(mb, off));
    }
    if (ln == 0) { s0[wv] = a2; s1[wv] = b2; s2_[wv] = ab; s3[wv] = mw; s4[wv] = mb; }
    __syncthreads();
    const float A2 = s0[0] + s0[1] + s0[2] + s0[3];
    const float B2 = s1[0] + s1[1] + s1[2] + s1[3];
    const float AB = s2_[0] + s2_[1] + s2_[2] + s2_[3];
    const float MW = fmaxf(fmaxf(s3[0], s3[1]), fmaxf(s3[2], s3[3]));
    const float MB = fmaxf(fmaxf(s4[0], s4[1]), fmaxf(s4[2], s4[3]));
    const float norm = sqrtf(B2);
    const float maxn = 1.0f - 1e-5f;          // (1-PROJ_EPS)/sqrt(c), c=1
    const float s = (norm > maxn) ? (maxn / norm) : 1.0f;
    const float amax_a = fmaxf(MW, 1e-30f);
    const float amax_p = fmaxf(MB * s, 1e-30f);
    if (t == 0) {
      p2v[o] = B2 * s * s; pav[o] = AB * s; anv[o] = sqrtf(A2);
      sav[o] = amax_a * (1.0f / 127.0f);
      spv[o] = amax_p * (1.0f / 127.0f);
    }
    const float inva = 127.0f / amax_a;
    const float invp = 127.0f / amax_p;
    a_q[(size_t)o * 256 + t] = pack4(
        __float2int_rn(w.x * inva), __float2int_rn(w.y * inva),
        __float2int_rn(w.z * inva), __float2int_rn(w.w * inva));
    p_q[(size_t)o * 256 + t] = pack4(
        __float2int_rn(b.x * s * invp), __float2int_rn(b.y * s * invp),
        __float2int_rn(b.z * s * invp), __float2int_rn(b.w * s * invp));
  } else {
    const int bi = blockIdx.x - O_DIM;
    const float4 v = ((const float4*)(x + (size_t)bi * K_DIM))[t];
    float ss = v.x*v.x + v.y*v.y + v.z*v.z + v.w*v.w;
    float mx = fmaxf(fmaxf(fabsf(v.x), fabsf(v.y)), fmaxf(fabsf(v.z), fabsf(v.w)));
    #pragma unroll
    for (int off = 32; off; off >>= 1) {
      ss += __shfl_down(ss, off);
      mx = fmaxf(mx, __shfl_down(mx, off));
    }
    if (ln == 0) { s0[wv] = ss; s3[wv] = mx; }
    __syncthreads();
    const float S2 = s0[0] + s0[1] + s0[2] + s0[3];
    const float MX = fmaxf(fmaxf(fmaxf(s3[0], s3[1]), fmaxf(s3[2], s3[3])), 1e-30f);
    if (t == 0) { x2v[bi] = S2; sxv[bi] = MX * (1.0f / 127.0f); }
    const float invx = 127.0f / MX;
    x_q[(size_t)bi * 256 + t] = pack4(
        __float2int_rn(v.x * invx), __float2int_rn(v.y * invx),
        __float2int_rn(v.z * invx), __float2int_rn(v.w * invx));
  }
}

// ---- main dual-GEMM (int8) + fused epilogue --------------------------------
// 8 waves (4M x 2N). BM=256, BN=128 (dual P/W), BK=128 i8 (128 B rows).
// LDS per buffer (BYTES): A[256*128]=32768 @0, P[128*128]=16384 @32768,
// W @49152; buffer stride 65536; 2 buffers = 128 KB. 8 K-tiles.
// XCD column-stripe: xcd = bid&7 owns nt in [xcd*4, xcd*4+4).
// One __syncthreads per K-tile; SGB pins [DS4 | MFMA16] chunk interleave.
__global__ __launch_bounds__(512, 2) void hdrl_main(
    const unsigned char* __restrict__ Xq,
    const unsigned char* __restrict__ Pq,
    const unsigned char* __restrict__ Wq,
    const float* __restrict__ x2v, const float* __restrict__ p2v,
    const float* __restrict__ pav, const float* __restrict__ anv,
    const float* __restrict__ sxv, const float* __restrict__ sav,
    const float* __restrict__ spv,
    float* __restrict__ out)
{
  extern __shared__ unsigned char lds[];

  const int bid   = blockIdx.x;
  const int xcd   = bid & 7;
  const int local = bid >> 3;                 // 0..127 per XCD
  const int nt    = xcd * 4 + (local & 3);    // 4 n-columns per XCD
  const int mt    = local >> 2;               // 0..31
  const int row0 = mt * 256, col0 = nt * 128;
  const int t    = threadIdx.x;
  const int wv   = t >> 6, lane = t & 63;
  const int wm   = wv >> 1, wn = wv & 1;      // 4M x 2N waves
  const int lrow = lane & 15, kg = lane >> 4;
  // fragment k-slice byte offsets (16B chunks, XOR swizzle): chunk = kk*4+kg
  const int kbs0 = ((kg)     ^ (lrow & 7)) * 16;
  const int kbs1 = ((4 + kg) ^ (lrow & 7)) * 16;

  // staging: thread t covers (row = q*64 + (t>>3), chunk = t&7), 16B chunks
  const int sr    = t >> 3;                    // 0..63
  const int scolB = ((t & 7) ^ (sr & 7)) * 16; // inverse-swizzled source col
  const unsigned char* gA = Xq + (size_t)(row0 + sr) * KB + scolB;
  const unsigned char* gP = Pq + (size_t)(col0 + sr) * KB + scolB;
  const unsigned char* gW = Wq + (size_t)(col0 + sr) * KB + scolB;

  i32x4 accp[4][4], acca[4][4];
  #pragma unroll
  for (int i = 0; i < 4; ++i)
    #pragma unroll
    for (int j = 0; j < 4; ++j) { accp[i][j] = (i32x4)0; acca[i][j] = (i32x4)0; }

#define STAGE_A(q) load_lds16(gA + (size_t)(q)*64*KB + k0n, (void*)&lds[nb + (q)*8192 + wv*1024])
#define STAGE_P(q) load_lds16(gP + (size_t)(q)*64*KB + k0n, (void*)&lds[nb + 32768 + (q)*8192 + wv*1024])
#define STAGE_W(q) load_lds16(gW + (size_t)(q)*64*KB + k0n, (void*)&lds[nb + 49152 + (q)*8192 + wv*1024])

  // prologue: stage tile 0 into buffer 0
  {
    const int nb = 0, k0n = 0;
    STAGE_A(0); STAGE_A(1); STAGE_A(2); STAGE_A(3);
    STAGE_P(0); STAGE_P(1); STAGE_W(0); STAGE_W(1);
  }
  __syncthreads();

  for (int kt = 0; kt < 8; ++kt) {
    const int cur = kt & 1;
    const int nb  = (cur ^ 1) * 65536;
    const int cb  = cur * 65536;
    const int k0n = (kt + 1) * 128;            // byte offset of next K-tile

    // stage next tile first: loads get the whole compute phase to land
    if (kt < 7) {
      STAGE_A(0); STAGE_A(1); STAGE_A(2); STAGE_A(3);
      STAGE_P(0); STAGE_P(1); STAGE_W(0); STAGE_W(1);
    }

    i32x4 af[4][2], bp[4][2], bw[4][2];
    #pragma unroll
    for (int i = 0; i < 4; ++i) {
      const int rb = cb + (wm*64 + i*16 + lrow) * 128;
      af[i][0] = *(const i32x4*)&lds[rb + kbs0];
      af[i][1] = *(const i32x4*)&lds[rb + kbs1];
    }
    {
      const int rb = (wn*64 + lrow) * 128;
      bp[0][0] = *(const i32x4*)&lds[cb + 32768 + rb + kbs0];
      bp[0][1] = *(const i32x4*)&lds[cb + 32768 + rb + kbs1];
      bw[0][0] = *(const i32x4*)&lds[cb + 49152 + rb + kbs0];
      bw[0][1] = *(const i32x4*)&lds[cb + 49152 + rb + kbs1];
    }
    // pin: the 12 warm-up DS_READs stay ahead of the MFMA stream
    __builtin_amdgcn_sched_group_barrier(0x100, 12, 0);   // DS_READ x12

    __builtin_amdgcn_s_setprio(1);
    #pragma unroll
    for (int j = 0; j < 4; ++j) {
      if (j < 3) {   // prefetch next j's B frags (4 DS_READ)
        const int rb = (wn*64 + (j+1)*16 + lrow) * 128;
        bp[j+1][0] = *(const i32x4*)&lds[cb + 32768 + rb + kbs0];
        bp[j+1][1] = *(const i32x4*)&lds[cb + 32768 + rb + kbs1];
        bw[j+1][0] = *(const i32x4*)&lds[cb + 49152 + rb + kbs0];
        bw[j+1][1] = *(const i32x4*)&lds[cb + 49152 + rb + kbs1];
      }
      #pragma unroll
      for (int i = 0; i < 4; ++i)
        #pragma unroll
        for (int kk = 0; kk < 2; ++kk)
          accp[i][j] = __builtin_amdgcn_mfma_i32_16x16x64_i8(af[i][kk], bp[j][kk], accp[i][j], 0, 0, 0);
      #pragma unroll
      for (int i = 0; i < 4; ++i)
        #pragma unroll
        for (int kk = 0; kk < 2; ++kk)
          acca[i][j] = __builtin_amdgcn_mfma_i32_16x16x64_i8(af[i][kk], bw[j][kk], acca[i][j], 0, 0, 0);
      // chunk stream: 4 DS_READ (next j) then the 16 MFMA of this j
      if (j < 3) __builtin_amdgcn_sched_group_barrier(0x100, 4, 0);  // DS_READ x4
      __builtin_amdgcn_sched_group_barrier(0x8, 16, 0);              // MFMA x16
    }
    __builtin_amdgcn_s_setprio(0);

    __syncthreads();   // drains vmcnt+lgkmcnt: next buffer fully resident
  }

  // fused epilogue: C/D layout col = lane&15, row = (lane>>4)*4 + reg.
  // px = accp*sx*sp, xa = acca*sx*sa (int32 exact -> fp32).
  // arg = 2*(Bc*xa - Aq*pa) / (Bc*(1-x2)*an); out = copysign(asinh|arg|,arg)*an
  float Bcj[4], paj[4], dja[4], lcj[4], spj[4], saj[4];
  #pragma unroll
  for (int j = 0; j < 4; ++j) {
    const int col = col0 + wn * 64 + j * 16 + lrow;
    const float Bc = 1.0f - p2v[col];
    const float an = anv[col];
    Bcj[j] = Bc; paj[j] = pav[col];
    dja[j] = Bc * an;                 // denom col factor
    lcj[j] = 0.69314718f * an;        // ln2 * a_norm
    spj[j] = spv[col]; saj[j] = sav[col];
  }
  #pragma unroll
  for (int i = 0; i < 4; ++i) {
    const int rbase = row0 + wm * 64 + i * 16 + kg * 4;
    #pragma unroll
    for (int r = 0; r < 4; ++r) {
      const int row = rbase + r;
      const float x2 = x2v[row];
      const float sx = sxv[row];
      const float Aqh = 1.0f + x2;
      const float omx = 1.0f - x2;
      float* orow = out + (size_t)row * O_DIM + col0 + wn * 64 + lrow;
      #pragma unroll
      for (int j = 0; j < 4; ++j) {
        const float px = (float)accp[i][j][r] * (sx * spj[j]);
        const float xa = (float)acca[i][j][r] * (sx * saj[j]);
        const float numer = Bcj[j] * xa - (Aqh - 2.0f * px) * paj[j];
        const float denom = dja[j] * omx + 1e-15f;
        const float arg = 2.0f * numer * frcp(denom);
        const float aa  = fabsf(arg);
        const float u   = aa + fsqrt_(__builtin_fmaf(aa, aa, 1.0f));
        orow[j * 16] = copysignf(flog2(u) * lcj[j], arg);
      }
    }
  }
#undef STAGE_A
#undef STAGE_P
#undef STAGE_W
}

extern "C" void kernel_launch(void* const* d_in, const int* in_sizes, int n_in,
                              void* d_out, int out_size, void* d_ws, size_t ws_size,
                              hipStream_t stream) {
  (void)in_sizes; (void)n_in; (void)out_size; (void)ws_size;
  const float* x = (const float*)d_in[0];
  const float* w = (const float*)d_in[1];
  const float* b = (const float*)d_in[2];
  float* out = (float*)d_out;

  char* ws = (char*)d_ws;
  int* x_q = (int*)ws;                                        //  8 MB (8192x1024 i8)
  int* p_q = (int*)(ws + (size_t) 8 * 1024 * 1024);           //  4 MB
  int* a_q = (int*)(ws + (size_t)12 * 1024 * 1024);           //  4 MB
  float* p2v = (float*)(ws + (size_t)16 * 1024 * 1024);
  float* pav = p2v + O_DIM;
  float* anv = pav + O_DIM;
  float* sav = anv + O_DIM;
  float* spv = sav + O_DIM;
  float* x2v = spv + O_DIM;
  float* sxv = x2v + B_DIM;

  prep_all<<<O_DIM + B_DIM, 256, 0, stream>>>(x, w, b, x_q, a_q, p_q,
                                              x2v, p2v, pav, anv,
                                              sxv, sav, spv);

  hipFuncSetAttribute((const void*)hdrl_main,
                      hipFuncAttributeMaxDynamicSharedMemorySize, 131072);
  const int grid = (B_DIM / 256) * (O_DIM / 128);   // 1024
  hdrl_main<<<grid, 512, 131072, stream>>>(
      (const unsigned char*)x_q, (const unsigned char*)p_q,
      (const unsigned char*)a_q, x2v, p2v, pav, anv, sxv, sav, spv, out);
}

// Round 16
// 76.793 us; speedup vs baseline: 2.1500x; 1.3193x over previous
//
#include <hip/hip_runtime.h>
#include <math.h>

// ---------------------------------------------------------------------------
// HDRL Poincare MLR, c=1 — SINGLE-GEMM form.
//   numer = Bc*xa - (1+x2-2px)*pa = <x, m> - (1+x2)*pa,
//     where m_o = Bc_o*a_o + 2*pa_o*p_o   (per-row combine, done in prep)
//   denom = Bc*(1-x2)*an + 1e-15;  arg = 2*numer/denom
//   out = copysign(asinh(|arg|), arg) * an
// R15: the dual GEMM was algebraically redundant — px,xa enter the output
//   ONLY via the linear combo above. One i8 GEMM S = x*M^T: GEMM ops halve
//   (137->68.7 Gops), B-side LDS reads halve (per-wave 24->16 ds_reads),
//   acc registers halve. Same verified i8 quantization (R14: absmax 0.172),
//   same staging/swizzle/SGB/XCD-stripe structure as R14.
// ---------------------------------------------------------------------------

#define B_DIM 8192
#define O_DIM 4096
#define K_DIM 1024
#define KB    1024   // bytes per row in i8

using i32x4 = __attribute__((ext_vector_type(4))) int;
using f32x4 = __attribute__((ext_vector_type(4))) float;

__device__ inline void load_lds16(const void* g, void* l) {
  __builtin_amdgcn_global_load_lds(
      (const __attribute__((address_space(1))) void*)g,
      (__attribute__((address_space(3))) void*)l, 16, 0, 0);
}

__device__ inline float frcp(float x)  { float r; asm("v_rcp_f32 %0, %1"  : "=v"(r) : "v"(x)); return r; }
__device__ inline float fsqrt_(float x){ float r; asm("v_sqrt_f32 %0, %1" : "=v"(r) : "v"(x)); return r; }
__device__ inline float flog2(float x) { float r; asm("v_log_f32 %0, %1"  : "=v"(r) : "v"(x)); return r; }

__device__ inline int pack4(int a, int b, int c, int d) {
  return (a & 0xFF) | ((b & 0xFF) << 8) | ((c & 0xFF) << 16) | (d << 24);
}

// ---- merged prep: blocks [0, O_DIM) build M rows; rest quantize x ----------
// O-row: stats (a2,b2,ab) -> s, Bc, pa; m = Bc*w + (2*pa*s)*b; rowmax(m);
// quantize m (q = round(v*127/rowmax), scale sm = rowmax/127).
__global__ __launch_bounds__(256) void prep_all(
    const float* __restrict__ x, const float* __restrict__ wgt,
    const float* __restrict__ bia,
    int* __restrict__ x_q, int* __restrict__ m_q,
    float* __restrict__ x2v, float* __restrict__ bcv,
    float* __restrict__ pav, float* __restrict__ anv,
    float* __restrict__ sxv, float* __restrict__ smv)
{
  const int t = threadIdx.x;
  const int wv = t >> 6, ln = t & 63;
  __shared__ float s0[4], s1[4], s2_[4];

  if (blockIdx.x < O_DIM) {
    const int o = blockIdx.x;
    const float4 w = ((const float4*)(wgt + (size_t)o * K_DIM))[t];
    const float4 b = ((const float4*)(bia + (size_t)o * K_DIM))[t];
    float a2 = w.x*w.x + w.y*w.y + w.z*w.z + w.w*w.w;
    float b2 = b.x*b.x + b.y*b.y + b.z*b.z + b.w*b.w;
    float ab = w.x*b.x + w.y*b.y + w.z*b.z + w.w*b.w;
    #pragma unroll
    for (int off = 32; off; off >>= 1) {
      a2 += __shfl_down(a2, off);
      b2 += __shfl_down(b2, off);
      ab += __shfl_down(ab, off);
    }
    if (ln == 0) { s0[wv] = a2; s1[wv] = b2; s2_[wv] = ab; }
    __syncthreads();
    const float A2 = s0[0] + s0[1] + s0[2] + s0[3];
    const float B2 = s1[0] + s1[1] + s1[2] + s1[3];
    const float AB = s2_[0] + s2_[1] + s2_[2] + s2_[3];
    const float norm = sqrtf(B2);
    const float maxn = 1.0f - 1e-5f;          // (1-PROJ_EPS)/sqrt(c), c=1
    const float s  = (norm > maxn) ? (maxn / norm) : 1.0f;
    const float Bc = 1.0f - B2 * s * s;       // 1 - |p|^2
    const float pa = AB * s;                  // <p, a>
    const float c2 = 2.0f * pa * s;           // coeff of b in m
    // m = Bc*w + c2*b  (this thread's 4 elements)
    float4 m;
    m.x = Bc * w.x + c2 * b.x;  m.y = Bc * w.y + c2 * b.y;
    m.z = Bc * w.z + c2 * b.z;  m.w = Bc * w.w + c2 * b.w;
    // second reduce: rowmax |m|
    float mm = fmaxf(fmaxf(fabsf(m.x), fabsf(m.y)), fmaxf(fabsf(m.z), fabsf(m.w)));
    #pragma unroll
    for (int off = 32; off; off >>= 1) mm = fmaxf(mm, __shfl_down(mm, off));
    __syncthreads();                          // reuse s0 safely
    if (ln == 0) s0[wv] = mm;
    __syncthreads();
    const float MM = fmaxf(fmaxf(fmaxf(s0[0], s0[1]), fmaxf(s0[2], s0[3])), 1e-30f);
    if (t == 0) {
      bcv[o] = Bc; pav[o] = pa; anv[o] = sqrtf(A2);
      smv[o] = MM * (1.0f / 127.0f);
    }
    const float inv = 127.0f / MM;
    m_q[(size_t)o * 256 + t] = pack4(
        __float2int_rn(m.x * inv), __float2int_rn(m.y * inv),
        __float2int_rn(m.z * inv), __float2int_rn(m.w * inv));
  } else {
    const int bi = blockIdx.x - O_DIM;
    const float4 v = ((const float4*)(x + (size_t)bi * K_DIM))[t];
    float ss = v.x*v.x + v.y*v.y + v.z*v.z + v.w*v.w;
    float mx = fmaxf(fmaxf(fabsf(v.x), fabsf(v.y)), fmaxf(fabsf(v.z), fabsf(v.w)));
    #pragma unroll
    for (int off = 32; off; off >>= 1) {
      ss += __shfl_down(ss, off);
      mx = fmaxf(mx, __shfl_down(mx, off));
    }
    if (ln == 0) { s0[wv] = ss; s1[wv] = mx; }
    __syncthreads();
    const float S2 = s0[0] + s0[1] + s0[2] + s0[3];
    const float MX = fmaxf(fmaxf(fmaxf(s1[0], s1[1]), fmaxf(s1[2], s1[3])), 1e-30f);
    if (t == 0) { x2v[bi] = S2; sxv[bi] = MX * (1.0f / 127.0f); }
    const float invx = 127.0f / MX;
    x_q[(size_t)bi * 256 + t] = pack4(
        __float2int_rn(v.x * invx), __float2int_rn(v.y * invx),
        __float2int_rn(v.z * invx), __float2int_rn(v.w * invx));
  }
}

// ---- main single-GEMM (int8) + fused epilogue ------------------------------
// 8 waves (4M x 2N). BM=256, BN=128, BK=128 i8 (128 B rows). 8 K-tiles.
// LDS per buffer (BYTES): A[256*128]=32768 @0, M[128*128]=16384 @32768;
// buffer stride 49152; 2 buffers = 96 KB.
// XCD column-stripe; SGB pins [DS2 | MFMA8] chunk interleave; one
// __syncthreads per K-tile (double buffer).
__global__ __launch_bounds__(512, 2) void hdrl_main(
    const unsigned char* __restrict__ Xq,
    const unsigned char* __restrict__ Mq,
    const float* __restrict__ x2v, const float* __restrict__ bcv,
    const float* __restrict__ pav, const float* __restrict__ anv,
    const float* __restrict__ sxv, const float* __restrict__ smv,
    float* __restrict__ out)
{
  extern __shared__ unsigned char lds[];

  const int bid   = blockIdx.x;
  const int xcd   = bid & 7;
  const int local = bid >> 3;                 // 0..127 per XCD
  const int nt    = xcd * 4 + (local & 3);    // 4 n-columns per XCD
  const int mt    = local >> 2;               // 0..31
  const int row0 = mt * 256, col0 = nt * 128;
  const int t    = threadIdx.x;
  const int wv   = t >> 6, lane = t & 63;
  const int wm   = wv >> 1, wn = wv & 1;      // 4M x 2N waves
  const int lrow = lane & 15, kg = lane >> 4;
  // fragment k-slice byte offsets (16B chunks, XOR swizzle): chunk = kk*4+kg
  const int kbs0 = ((kg)     ^ (lrow & 7)) * 16;
  const int kbs1 = ((4 + kg) ^ (lrow & 7)) * 16;

  // staging: thread t covers (row = q*64 + (t>>3), chunk = t&7), 16B chunks
  const int sr    = t >> 3;                    // 0..63
  const int scolB = ((t & 7) ^ (sr & 7)) * 16; // inverse-swizzled source col
  const unsigned char* gA = Xq + (size_t)(row0 + sr) * KB + scolB;
  const unsigned char* gM = Mq + (size_t)(col0 + sr) * KB + scolB;

  i32x4 acc[4][4];
  #pragma unroll
  for (int i = 0; i < 4; ++i)
    #pragma unroll
    for (int j = 0; j < 4; ++j) acc[i][j] = (i32x4)0;

#define STAGE_A(q) load_lds16(gA + (size_t)(q)*64*KB + k0n, (void*)&lds[nb + (q)*8192 + wv*1024])
#define STAGE_M(q) load_lds16(gM + (size_t)(q)*64*KB + k0n, (void*)&lds[nb + 32768 + (q)*8192 + wv*1024])

  // prologue: stage tile 0 into buffer 0
  {
    const int nb = 0, k0n = 0;
    STAGE_A(0); STAGE_A(1); STAGE_A(2); STAGE_A(3);
    STAGE_M(0); STAGE_M(1);
  }
  __syncthreads();

  for (int kt = 0; kt < 8; ++kt) {
    const int cur = kt & 1;
    const int nb  = (cur ^ 1) * 49152;
    const int cb  = cur * 49152;
    const int k0n = (kt + 1) * 128;            // byte offset of next K-tile

    // stage next tile first: loads get the whole compute phase to land
    if (kt < 7) {
      STAGE_A(0); STAGE_A(1); STAGE_A(2); STAGE_A(3);
      STAGE_M(0); STAGE_M(1);
    }

    i32x4 af[4][2], bm[4][2];
    #pragma unroll
    for (int i = 0; i < 4; ++i) {
      const int rb = cb + (wm*64 + i*16 + lrow) * 128;
      af[i][0] = *(const i32x4*)&lds[rb + kbs0];
      af[i][1] = *(const i32x4*)&lds[rb + kbs1];
    }
    {
      const int rb = (wn*64 + lrow) * 128;
      bm[0][0] = *(const i32x4*)&lds[cb + 32768 + rb + kbs0];
      bm[0][1] = *(const i32x4*)&lds[cb + 32768 + rb + kbs1];
    }
    // pin: the 10 warm-up DS_READs stay ahead of the MFMA stream
    __builtin_amdgcn_sched_group_barrier(0x100, 10, 0);   // DS_READ x10

    __builtin_amdgcn_s_setprio(1);
    #pragma unroll
    for (int j = 0; j < 4; ++j) {
      if (j < 3) {   // prefetch next j's M frags (2 DS_READ)
        const int rb = (wn*64 + (j+1)*16 + lrow) * 128;
        bm[j+1][0] = *(const i32x4*)&lds[cb + 32768 + rb + kbs0];
        bm[j+1][1] = *(const i32x4*)&lds[cb + 32768 + rb + kbs1];
      }
      #pragma unroll
      for (int i = 0; i < 4; ++i)
        #pragma unroll
        for (int kk = 0; kk < 2; ++kk)
          acc[i][j] = __builtin_amdgcn_mfma_i32_16x16x64_i8(af[i][kk], bm[j][kk], acc[i][j], 0, 0, 0);
      // chunk stream: 2 DS_READ (next j) then the 8 MFMA of this j
      if (j < 3) __builtin_amdgcn_sched_group_barrier(0x100, 2, 0);  // DS_READ x2
      __builtin_amdgcn_sched_group_barrier(0x8, 8, 0);               // MFMA x8
    }
    __builtin_amdgcn_s_setprio(0);

    __syncthreads();   // drains vmcnt+lgkmcnt: next buffer fully resident
  }

  // fused epilogue: C/D layout col = lane&15, row = (lane>>4)*4 + reg.
  // numer = S*sx*sm - (1+x2)*pa;  denom = Bc*an*(1-x2) + 1e-15
  // arg = 2*numer/denom;  out = copysign(asinh(|arg|), arg) * an
  float paj[4], dja[4], lcj[4], smj[4];
  #pragma unroll
  for (int j = 0; j < 4; ++j) {
    const int col = col0 + wn * 64 + j * 16 + lrow;
    const float Bc = bcv[col];
    const float an = anv[col];
    paj[j] = pav[col];
    dja[j] = Bc * an;                 // denom col factor
    lcj[j] = 0.69314718f * an;        // ln2 * a_norm
    smj[j] = smv[col];
  }
  #pragma unroll
  for (int i = 0; i < 4; ++i) {
    const int rbase = row0 + wm * 64 + i * 16 + kg * 4;
    #pragma unroll
    for (int r = 0; r < 4; ++r) {
      const int row = rbase + r;
      const float x2 = x2v[row];
      const float sx = sxv[row];
      const float Aqh = 1.0f + x2;
      const float omx = 1.0f - x2;
      float* orow = out + (size_t)row * O_DIM + col0 + wn * 64 + lrow;
      #pragma unroll
      for (int j = 0; j < 4; ++j) {
        const float S = (float)acc[i][j][r] * (sx * smj[j]);
        const float numer = S - Aqh * paj[j];
        const float denom = dja[j] * omx + 1e-15f;
        const float arg = 2.0f * numer * frcp(denom);
        const float aa  = fabsf(arg);
        const float u   = aa + fsqrt_(__builtin_fmaf(aa, aa, 1.0f));
        orow[j * 16] = copysignf(flog2(u) * lcj[j], arg);
      }
    }
  }
#undef STAGE_A
#undef STAGE_M
}

extern "C" void kernel_launch(void* const* d_in, const int* in_sizes, int n_in,
                              void* d_out, int out_size, void* d_ws, size_t ws_size,
                              hipStream_t stream) {
  (void)in_sizes; (void)n_in; (void)out_size; (void)ws_size;
  const float* x = (const float*)d_in[0];
  const float* w = (const float*)d_in[1];
  const float* b = (const float*)d_in[2];
  float* out = (float*)d_out;

  char* ws = (char*)d_ws;
  int* x_q = (int*)ws;                                        //  8 MB (8192x1024 i8)
  int* m_q = (int*)(ws + (size_t) 8 * 1024 * 1024);           //  4 MB (4096x1024 i8)
  float* bcv = (float*)(ws + (size_t)12 * 1024 * 1024);
  float* pav = bcv + O_DIM;
  float* anv = pav + O_DIM;
  float* smv = anv + O_DIM;
  float* x2v = smv + O_DIM;
  float* sxv = x2v + B_DIM;

  prep_all<<<O_DIM + B_DIM, 256, 0, stream>>>(x, w, b, x_q, m_q,
                                              x2v, bcv, pav, anv, sxv, smv);

  hipFuncSetAttribute((const void*)hdrl_main,
                      hipFuncAttributeMaxDynamicSharedMemorySize, 98304);
  const int grid = (B_DIM / 256) * (O_DIM / 128);   // 1024
  hdrl_main<<<grid, 512, 98304, stream>>>(
      (const unsigned char*)x_q, (const unsigned char*)m_q,
      x2v, bcv, pav, anv, sxv, smv, out);
}

// Round 17
// 70.503 us; speedup vs baseline: 2.3418x; 1.0892x over previous
//
#include <hip/hip_runtime.h>
#include <math.h>

// ---------------------------------------------------------------------------
// HDRL Poincare MLR, c=1 — SINGLE-GEMM form (R15-verified, absmax 0.164).
//   numer = <x, m> - (1+x2)*pa,  m_o = Bc_o*a_o + 2*pa_o*p_o  (prep)
//   denom = Bc*(1-x2)*an + 1e-15;  arg = 2*numer/denom
//   out = copysign(asinh(|arg|), arg) * an
//
// R16: geometry cut of LDS-port bytes (the measured ~50 B/cyc binding
//   resource). Port bytes/block = K[(BM·gN+BN·gM)+(BM+BN)]. Going
//   256x128/(4Mx2N) -> 256x256/(2Mx4N) with wave=128x64 (acc 128 regs,
//   enabled by single-GEMM's halved accumulators): blocks 1024->512,
//   total port 1.47 GB -> 1.07 GB (-27%). i-outer MFMA loop keeps live
//   VGPR ~190 (acc 128 + bm 32 + af rolling) -> 2 waves/SIMD, no spill.
//   All R15-verified pieces unchanged: i8 quant, staging+XOR swizzle,
//   XCD stripe (now 2 n-cols/XCD), fast epilogue.
// ---------------------------------------------------------------------------

#define B_DIM 8192
#define O_DIM 4096
#define K_DIM 1024
#define KB    1024   // bytes per row in i8

using i32x4 = __attribute__((ext_vector_type(4))) int;

__device__ inline void load_lds16(const void* g, void* l) {
  __builtin_amdgcn_global_load_lds(
      (const __attribute__((address_space(1))) void*)g,
      (__attribute__((address_space(3))) void*)l, 16, 0, 0);
}

__device__ inline float frcp(float x)  { float r; asm("v_rcp_f32 %0, %1"  : "=v"(r) : "v"(x)); return r; }
__device__ inline float fsqrt_(float x){ float r; asm("v_sqrt_f32 %0, %1" : "=v"(r) : "v"(x)); return r; }
__device__ inline float flog2(float x) { float r; asm("v_log_f32 %0, %1"  : "=v"(r) : "v"(x)); return r; }

__device__ inline int pack4(int a, int b, int c, int d) {
  return (a & 0xFF) | ((b & 0xFF) << 8) | ((c & 0xFF) << 16) | (d << 24);
}

// ---- merged prep: blocks [0, O_DIM) build M rows; rest quantize x ----------
__global__ __launch_bounds__(256) void prep_all(
    const float* __restrict__ x, const float* __restrict__ wgt,
    const float* __restrict__ bia,
    int* __restrict__ x_q, int* __restrict__ m_q,
    float* __restrict__ x2v, float* __restrict__ bcv,
    float* __restrict__ pav, float* __restrict__ anv,
    float* __restrict__ sxv, float* __restrict__ smv)
{
  const int t = threadIdx.x;
  const int wv = t >> 6, ln = t & 63;
  __shared__ float s0[4], s1[4], s2_[4];

  if (blockIdx.x < O_DIM) {
    const int o = blockIdx.x;
    const float4 w = ((const float4*)(wgt + (size_t)o * K_DIM))[t];
    const float4 b = ((const float4*)(bia + (size_t)o * K_DIM))[t];
    float a2 = w.x*w.x + w.y*w.y + w.z*w.z + w.w*w.w;
    float b2 = b.x*b.x + b.y*b.y + b.z*b.z + b.w*b.w;
    float ab = w.x*b.x + w.y*b.y + w.z*b.z + w.w*b.w;
    #pragma unroll
    for (int off = 32; off; off >>= 1) {
      a2 += __shfl_down(a2, off);
      b2 += __shfl_down(b2, off);
      ab += __shfl_down(ab, off);
    }
    if (ln == 0) { s0[wv] = a2; s1[wv] = b2; s2_[wv] = ab; }
    __syncthreads();
    const float A2 = s0[0] + s0[1] + s0[2] + s0[3];
    const float B2 = s1[0] + s1[1] + s1[2] + s1[3];
    const float AB = s2_[0] + s2_[1] + s2_[2] + s2_[3];
    const float norm = sqrtf(B2);
    const float maxn = 1.0f - 1e-5f;          // (1-PROJ_EPS)/sqrt(c), c=1
    const float s  = (norm > maxn) ? (maxn / norm) : 1.0f;
    const float Bc = 1.0f - B2 * s * s;       // 1 - |p|^2
    const float pa = AB * s;                  // <p, a>
    const float c2 = 2.0f * pa * s;           // coeff of b in m
    float4 m;
    m.x = Bc * w.x + c2 * b.x;  m.y = Bc * w.y + c2 * b.y;
    m.z = Bc * w.z + c2 * b.z;  m.w = Bc * w.w + c2 * b.w;
    float mm = fmaxf(fmaxf(fabsf(m.x), fabsf(m.y)), fmaxf(fabsf(m.z), fabsf(m.w)));
    #pragma unroll
    for (int off = 32; off; off >>= 1) mm = fmaxf(mm, __shfl_down(mm, off));
    __syncthreads();
    if (ln == 0) s0[wv] = mm;
    __syncthreads();
    const float MM = fmaxf(fmaxf(fmaxf(s0[0], s0[1]), fmaxf(s0[2], s0[3])), 1e-30f);
    if (t == 0) {
      bcv[o] = Bc; pav[o] = pa; anv[o] = sqrtf(A2);
      smv[o] = MM * (1.0f / 127.0f);
    }
    const float inv = 127.0f / MM;
    m_q[(size_t)o * 256 + t] = pack4(
        __float2int_rn(m.x * inv), __float2int_rn(m.y * inv),
        __float2int_rn(m.z * inv), __float2int_rn(m.w * inv));
  } else {
    const int bi = blockIdx.x - O_DIM;
    const float4 v = ((const float4*)(x + (size_t)bi * K_DIM))[t];
    float ss = v.x*v.x + v.y*v.y + v.z*v.z + v.w*v.w;
    float mx = fmaxf(fmaxf(fabsf(v.x), fabsf(v.y)), fmaxf(fabsf(v.z), fabsf(v.w)));
    #pragma unroll
    for (int off = 32; off; off >>= 1) {
      ss += __shfl_down(ss, off);
      mx = fmaxf(mx, __shfl_down(mx, off));
    }
    if (ln == 0) { s0[wv] = ss; s1[wv] = mx; }
    __syncthreads();
    const float S2 = s0[0] + s0[1] + s0[2] + s0[3];
    const float MX = fmaxf(fmaxf(fmaxf(s1[0], s1[1]), fmaxf(s1[2], s1[3])), 1e-30f);
    if (t == 0) { x2v[bi] = S2; sxv[bi] = MX * (1.0f / 127.0f); }
    const float invx = 127.0f / MX;
    x_q[(size_t)bi * 256 + t] = pack4(
        __float2int_rn(v.x * invx), __float2int_rn(v.y * invx),
        __float2int_rn(v.z * invx), __float2int_rn(v.w * invx));
  }
}

// ---- main single-GEMM (int8) + fused epilogue ------------------------------
// 8 waves (2M x 4N). BM=256, BN=256, BK=128 i8 (128 B rows). 8 K-tiles.
// Wave = 128 rows x 64 cols: acc[8][4] i32x4 = 128 regs.
// LDS per buffer (BYTES): A[256*128]=32768 @0, M[256*128]=32768 @32768;
// buffer stride 65536; 2 buffers = 128 KB.
// XCD column-stripe: xcd owns 2 n-columns. One __syncthreads per K-tile.
// MFMA loop i-outer: bm[4][2] resident (32 regs), af rolling (2 frags live).
__global__ __launch_bounds__(512, 2) void hdrl_main(
    const unsigned char* __restrict__ Xq,
    const unsigned char* __restrict__ Mq,
    const float* __restrict__ x2v, const float* __restrict__ bcv,
    const float* __restrict__ pav, const float* __restrict__ anv,
    const float* __restrict__ sxv, const float* __restrict__ smv,
    float* __restrict__ out)
{
  extern __shared__ unsigned char lds[];

  const int bid   = blockIdx.x;
  const int xcd   = bid & 7;
  const int local = bid >> 3;                 // 0..63 per XCD
  const int nt    = xcd * 2 + (local & 1);    // 2 n-columns per XCD
  const int mt    = local >> 1;               // 0..31
  const int row0 = mt * 256, col0 = nt * 256;
  const int t    = threadIdx.x;
  const int wv   = t >> 6, lane = t & 63;
  const int wm   = wv >> 2, wn = wv & 3;      // 2M x 4N waves
  const int lrow = lane & 15, kg = lane >> 4;
  // fragment k-slice byte offsets (16B chunks, XOR swizzle): chunk = kk*4+kg
  const int kbs0 = ((kg)     ^ (lrow & 7)) * 16;
  const int kbs1 = ((4 + kg) ^ (lrow & 7)) * 16;

  // staging: thread t covers (row = q*64 + (t>>3), chunk = t&7), 16B chunks
  const int sr    = t >> 3;                    // 0..63
  const int scolB = ((t & 7) ^ (sr & 7)) * 16; // inverse-swizzled source col
  const unsigned char* gA = Xq + (size_t)(row0 + sr) * KB + scolB;
  const unsigned char* gM = Mq + (size_t)(col0 + sr) * KB + scolB;

  i32x4 acc[8][4];
  #pragma unroll
  for (int i = 0; i < 8; ++i)
    #pragma unroll
    for (int j = 0; j < 4; ++j) acc[i][j] = (i32x4)0;

#define STAGE_A(q) load_lds16(gA + (size_t)(q)*64*KB + k0n, (void*)&lds[nb + (q)*8192 + wv*1024])
#define STAGE_M(q) load_lds16(gM + (size_t)(q)*64*KB + k0n, (void*)&lds[nb + 32768 + (q)*8192 + wv*1024])

  // prologue: stage tile 0 into buffer 0
  {
    const int nb = 0, k0n = 0;
    STAGE_A(0); STAGE_A(1); STAGE_A(2); STAGE_A(3);
    STAGE_M(0); STAGE_M(1); STAGE_M(2); STAGE_M(3);
  }
  __syncthreads();

  for (int kt = 0; kt < 8; ++kt) {
    const int cur = kt & 1;
    const int nb  = (cur ^ 1) * 65536;
    const int cb  = cur * 65536;
    const int k0n = (kt + 1) * 128;            // byte offset of next K-tile

    // stage next tile first: loads get the whole compute phase to land
    if (kt < 7) {
      STAGE_A(0); STAGE_A(1); STAGE_A(2); STAGE_A(3);
      STAGE_M(0); STAGE_M(1); STAGE_M(2); STAGE_M(3);
    }

    // B fragments resident (8 reads, 32 regs); A fragments rolling
    i32x4 bm[4][2], af[8][2];
    #pragma unroll
    for (int j = 0; j < 4; ++j) {
      const int rb = cb + 32768 + (wn*64 + j*16 + lrow) * 128;
      bm[j][0] = *(const i32x4*)&lds[rb + kbs0];
      bm[j][1] = *(const i32x4*)&lds[rb + kbs1];
    }
    {
      const int rb = cb + (wm*128 + lrow) * 128;
      af[0][0] = *(const i32x4*)&lds[rb + kbs0];
      af[0][1] = *(const i32x4*)&lds[rb + kbs1];
    }
    // pin: the 10 warm-up DS_READs stay ahead of the MFMA stream
    __builtin_amdgcn_sched_group_barrier(0x100, 10, 0);   // DS_READ x10

    __builtin_amdgcn_s_setprio(1);
    #pragma unroll
    for (int i = 0; i < 8; ++i) {
      if (i < 7) {   // prefetch next i's A frags (2 DS_READ)
        const int rb = cb + (wm*128 + (i+1)*16 + lrow) * 128;
        af[i+1][0] = *(const i32x4*)&lds[rb + kbs0];
        af[i+1][1] = *(const i32x4*)&lds[rb + kbs1];
      }
      #pragma unroll
      for (int j = 0; j < 4; ++j)
        #pragma unroll
        for (int kk = 0; kk < 2; ++kk)
          acc[i][j] = __builtin_amdgcn_mfma_i32_16x16x64_i8(af[i][kk], bm[j][kk], acc[i][j], 0, 0, 0);
      // chunk stream: 2 DS_READ (next i) then the 8 MFMA of this i
      if (i < 7) __builtin_amdgcn_sched_group_barrier(0x100, 2, 0);  // DS_READ x2
      __builtin_amdgcn_sched_group_barrier(0x8, 8, 0);               // MFMA x8
    }
    __builtin_amdgcn_s_setprio(0);

    __syncthreads();   // drains vmcnt+lgkmcnt: next buffer fully resident
  }

  // fused epilogue: C/D layout col = lane&15, row = (lane>>4)*4 + reg.
  // numer = S*sx*sm - (1+x2)*pa;  denom = Bc*an*(1-x2) + 1e-15
  // arg = 2*numer/denom;  out = copysign(asinh(|arg|), arg) * an
  float paj[4], dja[4], lcj[4], smj[4];
  #pragma unroll
  for (int j = 0; j < 4; ++j) {
    const int col = col0 + wn * 64 + j * 16 + lrow;
    const float Bc = bcv[col];
    const float an = anv[col];
    paj[j] = pav[col];
    dja[j] = Bc * an;                 // denom col factor
    lcj[j] = 0.69314718f * an;        // ln2 * a_norm
    smj[j] = smv[col];
  }
  #pragma unroll
  for (int i = 0; i < 8; ++i) {
    const int rbase = row0 + wm * 128 + i * 16 + kg * 4;
    #pragma unroll
    for (int r = 0; r < 4; ++r) {
      const int row = rbase + r;
      const float x2 = x2v[row];
      const float sx = sxv[row];
      const float Aqh = 1.0f + x2;
      const float omx = 1.0f - x2;
      float* orow = out + (size_t)row * O_DIM + col0 + wn * 64 + lrow;
      #pragma unroll
      for (int j = 0; j < 4; ++j) {
        const float S = (float)acc[i][j][r] * (sx * smj[j]);
        const float numer = S - Aqh * paj[j];
        const float denom = dja[j] * omx + 1e-15f;
        const float arg = 2.0f * numer * frcp(denom);
        const float aa  = fabsf(arg);
        const float u   = aa + fsqrt_(__builtin_fmaf(aa, aa, 1.0f));
        orow[j * 16] = copysignf(flog2(u) * lcj[j], arg);
      }
    }
  }
#undef STAGE_A
#undef STAGE_M
}

extern "C" void kernel_launch(void* const* d_in, const int* in_sizes, int n_in,
                              void* d_out, int out_size, void* d_ws, size_t ws_size,
                              hipStream_t stream) {
  (void)in_sizes; (void)n_in; (void)out_size; (void)ws_size;
  const float* x = (const float*)d_in[0];
  const float* w = (const float*)d_in[1];
  const float* b = (const float*)d_in[2];
  float* out = (float*)d_out;

  char* ws = (char*)d_ws;
  int* x_q = (int*)ws;                                        //  8 MB (8192x1024 i8)
  int* m_q = (int*)(ws + (size_t) 8 * 1024 * 1024);           //  4 MB (4096x1024 i8)
  float* bcv = (float*)(ws + (size_t)12 * 1024 * 1024);
  float* pav = bcv + O_DIM;
  float* anv = pav + O_DIM;
  float* smv = anv + O_DIM;
  float* x2v = smv + O_DIM;
  float* sxv = x2v + B_DIM;

  prep_all<<<O_DIM + B_DIM, 256, 0, stream>>>(x, w, b, x_q, m_q,
                                              x2v, bcv, pav, anv, sxv, smv);

  hipFuncSetAttribute((const void*)hdrl_main,
                      hipFuncAttributeMaxDynamicSharedMemorySize, 131072);
  const int grid = (B_DIM / 256) * (O_DIM / 256);   // 512
  hdrl_main<<<grid, 512, 131072, stream>>>(
      (const unsigned char*)x_q, (const unsigned char*)m_q,
      x2v, bcv, pav, anv, sxv, smv, out);
}